// Round 2
// baseline (428.037 us; speedup 1.0000x reference)
//
#include <hip/hip_runtime.h>

#define BB 2
#define TT 2048
#define DD 1024
#define NN 16
#define HH 64
#define NHC 1024   // N*H
#define CAPV 50.0f

typedef float f32x4 __attribute__((ext_vector_type(4)));
typedef __bf16 bf16x8 __attribute__((ext_vector_type(8)));
typedef unsigned short u16x8 __attribute__((ext_vector_type(8)));

// round-to-nearest-even f32 -> bf16 bits
__device__ __forceinline__ unsigned short f2bf(float f) {
  unsigned u = __builtin_bit_cast(unsigned, f);
  unsigned r = (u + 0x7fffu + ((u >> 16) & 1u)) >> 16;
  return (unsigned short)r;
}

// async global->LDS, 16B per lane; LDS dest must be wave-linear (base + lane*16)
__device__ __forceinline__ void gld16(void* lds, const void* g) {
  __builtin_amdgcn_global_load_lds(
      (__attribute__((address_space(1))) void*)(const_cast<void*>(g)),
      (__attribute__((address_space(3))) void*)(lds), 16, 0, 0);
}

// ---------------------------------------------------------------------------
// f32 -> bf16 convert of the three input vectors
__global__ __launch_bounds__(256) void conv_inputs(
    const float* __restrict__ q, const float* __restrict__ k, const float* __restrict__ v,
    unsigned short* __restrict__ qo, unsigned short* __restrict__ ko, unsigned short* __restrict__ vo) {
  const float* src = blockIdx.z == 0 ? q : (blockIdx.z == 1 ? k : v);
  unsigned short* dst = blockIdx.z == 0 ? qo : (blockIdx.z == 1 ? ko : vo);
  size_t i = ((size_t)blockIdx.x * 256 + threadIdx.x) * 8;
  float4 a = *(const float4*)&src[i];
  float4 c = *(const float4*)&src[i + 4];
  u16x8 o;
  o[0] = f2bf(a.x); o[1] = f2bf(a.y); o[2] = f2bf(a.z); o[3] = f2bf(a.w);
  o[4] = f2bf(c.x); o[5] = f2bf(c.y); o[6] = f2bf(c.z); o[7] = f2bf(c.w);
  *(u16x8*)&dst[i] = o;
}

// transpose 1024x1024 f32 -> 1024x1024 bf16 (dst = src^T), z picks which weight
__global__ __launch_bounds__(256) void transpose_w(
    const float* __restrict__ wq, const float* __restrict__ wk,
    const float* __restrict__ wv, const float* __restrict__ wo,
    unsigned short* __restrict__ oq, unsigned short* __restrict__ ok,
    unsigned short* __restrict__ ov, unsigned short* __restrict__ oo) {
  __shared__ float tile[64][65];
  int z = blockIdx.z;
  const float* src = z == 0 ? wq : z == 1 ? wk : z == 2 ? wv : wo;
  unsigned short* dst = z == 0 ? oq : z == 1 ? ok : z == 2 ? ov : oo;
  int r0 = blockIdx.y * 64, c0 = blockIdx.x * 64;
  int tid = threadIdx.x;
#pragma unroll
  for (int i = 0; i < 16; ++i) {
    int idx = tid + 256 * i; int r = idx >> 6, c = idx & 63;
    tile[r][c] = src[(size_t)(r0 + r) * 1024 + c0 + c];
  }
  __syncthreads();
#pragma unroll
  for (int i = 0; i < 16; ++i) {
    int idx = tid + 256 * i; int rr = idx >> 6, cc = idx & 63;
    dst[(size_t)(c0 + rr) * 1024 + r0 + cc] = f2bf(tile[cc][rr]);
  }
}

// v [B,S,N,H] bf16 -> vT [B,N,H,S] bf16
__global__ __launch_bounds__(256) void transpose_v(
    const unsigned short* __restrict__ vb, unsigned short* __restrict__ vT) {
  __shared__ unsigned short tl[64][80];
  int s0 = blockIdx.x * 64, n = blockIdx.y, b = blockIdx.z;
  int tid = threadIdx.x;
  const size_t base = (size_t)b * TT * NHC + (size_t)n * HH;
#pragma unroll
  for (int i = 0; i < 2; ++i) {
    int c = tid + 256 * i; int r = c >> 3, g = c & 7;
    *(u16x8*)&tl[r][g * 8] = *(const u16x8*)&vb[base + (size_t)(s0 + r) * NHC + g * 8];
  }
  __syncthreads();
  const size_t vtb = (size_t)(b * NN + n) * HH * TT;
#pragma unroll
  for (int i = 0; i < 2; ++i) {
    int c = tid + 256 * i; int h = c >> 3, sg = c & 7;
    u16x8 w;
#pragma unroll
    for (int j = 0; j < 8; ++j) w[j] = tl[sg * 8 + j][h];
    *(u16x8*)&vT[vtb + (size_t)h * TT + s0 + sg * 8] = w;
  }
}

// ---------------------------------------------------------------------------
// 128x128-tile bf16 GEMM, K=1024, BK=64, 4 waves (2x2), XOR-swizzled LDS.
// C[row, col] = sum_k A[row,k] * BT[col,k]; epilogue (acc+bias)*scale.
template <int OUT_F32>
__global__ __launch_bounds__(256) void gemm128(
    const unsigned short* __restrict__ A, const unsigned short* __restrict__ BT,
    const float* __restrict__ bias, void* __restrict__ Cout, float scale) {
  __shared__ unsigned short As[128 * 64];
  __shared__ unsigned short Bs[128 * 64];
  const int tid = threadIdx.x, lane = tid & 63, wave = tid >> 6;
  const int wm = wave >> 1, wn = wave & 1;
  const int l15 = lane & 15, l4 = lane >> 4;
  const int row0 = blockIdx.y * 128, col0 = blockIdx.x * 128;
  f32x4 acc[4][4] = {};
  for (int kt = 0; kt < 16; ++kt) {
    if (kt) __syncthreads();
#pragma unroll
    for (int i = 0; i < 4; ++i) {
      int c = tid + 256 * i; int r = c >> 3, g = (c & 7) ^ (r & 7);
      gld16(&As[c * 8], &A[(size_t)(row0 + r) * 1024 + kt * 64 + g * 8]);
    }
#pragma unroll
    for (int i = 0; i < 4; ++i) {
      int c = tid + 256 * i; int r = c >> 3, g = (c & 7) ^ (r & 7);
      gld16(&Bs[c * 8], &BT[(size_t)(col0 + r) * 1024 + kt * 64 + g * 8]);
    }
    __syncthreads();
#pragma unroll
    for (int ks = 0; ks < 2; ++ks) {
      bf16x8 af[4], bfr[4];
#pragma unroll
      for (int m = 0; m < 4; ++m) {
        int r = wm * 64 + m * 16 + l15;
        int ch = (ks * 4 + l4) ^ (r & 7);
        af[m] = *(const bf16x8*)&As[r * 64 + ch * 8];
      }
#pragma unroll
      for (int n = 0; n < 4; ++n) {
        int r = wn * 64 + n * 16 + l15;
        int ch = (ks * 4 + l4) ^ (r & 7);
        bfr[n] = *(const bf16x8*)&Bs[r * 64 + ch * 8];
      }
#pragma unroll
      for (int m = 0; m < 4; ++m)
#pragma unroll
        for (int n = 0; n < 4; ++n)
          acc[m][n] = __builtin_amdgcn_mfma_f32_16x16x32_bf16(af[m], bfr[n], acc[m][n], 0, 0, 0);
    }
  }
#pragma unroll
  for (int m = 0; m < 4; ++m)
#pragma unroll
    for (int n = 0; n < 4; ++n) {
      int col = col0 + wn * 64 + n * 16 + l15;
      float bv = bias[col];
#pragma unroll
      for (int r = 0; r < 4; ++r) {
        int row = row0 + wm * 64 + m * 16 + l4 * 4 + r;
        float v = (acc[m][n][r] + bv) * scale;
        if (OUT_F32) ((float*)Cout)[(size_t)row * 1024 + col] = v;
        else ((unsigned short*)Cout)[(size_t)row * 1024 + col] = f2bf(v);
      }
    }
}

// ---------------------------------------------------------------------------
// Fused attention: denom loop + probs/PV loop in one kernel, zero barriers.
// 4 waves/block; wave w owns q-rows [t0+32w, t0+32w+32), all 128 s-cols/tile.
// K,V fragments read directly from global (per-head K,V = 256KB, L2-resident).
// P transpose goes through per-wave LDS (padded stride 136 shorts, no swizzle).
__global__ __launch_bounds__(256, 2) void fused_attn(
    const unsigned short* __restrict__ qb, const unsigned short* __restrict__ kb,
    const unsigned short* __restrict__ vT, float* __restrict__ probs,
    unsigned short* __restrict__ enc) {
  __shared__ unsigned short P_lds[4][32][136];
  const int tid = threadIdx.x, lane = tid & 63, wave = tid >> 6;
  const int l15 = lane & 15, l4 = lane >> 4;
  // XCD-chunked bijective swizzle: 512 blocks, 64 per XCD = 4 full heads
  const int bid = blockIdx.x;
  const int logical = (bid & 7) * 64 + (bid >> 3);
  const int bt = logical & 15, head = logical >> 4;
  const int n = head & 15, b = head >> 4;
  const int t0 = bt * 128;
  const int wrow0 = t0 + wave * 32;
  const size_t base = (size_t)b * TT * NHC + (size_t)n * HH;
  const size_t vtb = (size_t)(b * NN + n) * HH * TT;
  const size_t prow = (size_t)(b * NN + n) * TT;

  // Q fragments (rows wave-local): qf[m][ks], row = wrow0 + m*16 + l15
  bf16x8 qf[2][2];
#pragma unroll
  for (int m = 0; m < 2; ++m)
#pragma unroll
    for (int ks = 0; ks < 2; ++ks)
      qf[m][ks] = *(const bf16x8*)&qb[base + (size_t)(wrow0 + m * 16 + l15) * NHC + ks * 32 + l4 * 8];

  // ---- loop 1: denominator ----
  float psum[2][4] = {};
#pragma unroll 1
  for (int st = 0; st < 16; ++st) {
    const int s0 = st * 128;
    f32x4 acc[2][8] = {};
#pragma unroll
    for (int ks = 0; ks < 2; ++ks) {
      bf16x8 kf[8];
#pragma unroll
      for (int nf = 0; nf < 8; ++nf)
        kf[nf] = *(const bf16x8*)&kb[base + (size_t)(s0 + nf * 16 + l15) * NHC + ks * 32 + l4 * 8];
#pragma unroll
      for (int m = 0; m < 2; ++m)
#pragma unroll
        for (int nf = 0; nf < 8; ++nf)
          acc[m][nf] = __builtin_amdgcn_mfma_f32_16x16x32_bf16(qf[m][ks], kf[nf], acc[m][nf], 0, 0, 0);
    }
#pragma unroll
    for (int m = 0; m < 2; ++m)
#pragma unroll
      for (int nf = 0; nf < 8; ++nf)
#pragma unroll
        for (int r = 0; r < 4; ++r) {
          float l = acc[m][nf][r];
          float u = __expf(l * (2.0f / CAPV));
          float ct = CAPV * (u - 1.0f) * __builtin_amdgcn_rcpf(u + 1.0f);
          psum[m][r] += __expf(ct);
        }
  }
  float dinv[2][4];
#pragma unroll
  for (int m = 0; m < 2; ++m)
#pragma unroll
    for (int r = 0; r < 4; ++r) {
      float s = psum[m][r];
      s += __shfl_xor(s, 1);
      s += __shfl_xor(s, 2);
      s += __shfl_xor(s, 4);
      s += __shfl_xor(s, 8);
      dinv[m][r] = 1.0f / s;
    }

  // ---- loop 2: probs write + PV ----
  f32x4 eacc[2][4] = {};
#pragma unroll 1
  for (int st = 0; st < 16; ++st) {
    const int s0 = st * 128;
    f32x4 acc[2][8] = {};
#pragma unroll
    for (int ks = 0; ks < 2; ++ks) {
      bf16x8 kf[8];
#pragma unroll
      for (int nf = 0; nf < 8; ++nf)
        kf[nf] = *(const bf16x8*)&kb[base + (size_t)(s0 + nf * 16 + l15) * NHC + ks * 32 + l4 * 8];
#pragma unroll
      for (int m = 0; m < 2; ++m)
#pragma unroll
        for (int nf = 0; nf < 8; ++nf)
          acc[m][nf] = __builtin_amdgcn_mfma_f32_16x16x32_bf16(qf[m][ks], kf[nf], acc[m][nf], 0, 0, 0);
    }
    // exp + pack to bf16 pairs (DPP xor1) + per-wave LDS write
    const bool evl = (l15 & 1) == 0;
#pragma unroll
    for (int m = 0; m < 2; ++m)
#pragma unroll
      for (int r = 0; r < 4; ++r) {
        float ev[8], pw[8];
#pragma unroll
        for (int nf = 0; nf < 8; ++nf) {
          float l = acc[m][nf][r];
          float u = __expf(l * (2.0f / CAPV));
          float ct = CAPV * (u - 1.0f) * __builtin_amdgcn_rcpf(u + 1.0f);
          ev[nf] = __expf(ct);
        }
#pragma unroll
        for (int nf = 0; nf < 8; ++nf) pw[nf] = __shfl_xor(ev[nf], 1);
        const int row = m * 16 + l4 * 4 + r;
        unsigned short* Pr = &P_lds[wave][row][0];
#pragma unroll
        for (int j = 0; j < 4; ++j) {
          float lo = evl ? ev[j] : pw[j + 4];
          float hi = evl ? pw[j] : ev[j + 4];
          unsigned pk;
          asm("v_cvt_pk_bf16_f32 %0, %1, %2" : "=v"(pk) : "v"(lo), "v"(hi));
          int col = (evl ? j * 16 : (j + 4) * 16) + (l15 & ~1);
          *(unsigned*)&Pr[col] = pk;
        }
      }
    asm volatile("s_waitcnt lgkmcnt(0)" ::: "memory");
    // coalesced probs write from LDS (normalized)
#pragma unroll
    for (int m = 0; m < 2; ++m)
#pragma unroll
      for (int r = 0; r < 4; ++r) {
        const int row = m * 16 + l4 * 4 + r;
        bf16x8 p8 = *(const bf16x8*)&P_lds[wave][row][l15 * 8];
        float dv = dinv[m][r];
        f32x4 o0, o1;
#pragma unroll
        for (int j = 0; j < 4; ++j) { o0[j] = (float)p8[j] * dv; o1[j] = (float)p8[j + 4] * dv; }
        size_t off = (prow + (size_t)(wrow0 + row)) * TT + s0 + l15 * 8;
        *(f32x4*)&probs[off] = o0;
        *(f32x4*)&probs[off + 4] = o1;
      }
    // PV: A = P (wave-local LDS), B = vT fragments direct from global
#pragma unroll
    for (int kst = 0; kst < 4; ++kst) {
      bf16x8 pa[2], vf[4];
#pragma unroll
      for (int m2 = 0; m2 < 2; ++m2)
        pa[m2] = *(const bf16x8*)&P_lds[wave][m2 * 16 + l15][kst * 32 + l4 * 8];
#pragma unroll
      for (int h4 = 0; h4 < 4; ++h4)
        vf[h4] = *(const bf16x8*)&vT[vtb + (size_t)(h4 * 16 + l15) * TT + s0 + kst * 32 + l4 * 8];
#pragma unroll
      for (int m2 = 0; m2 < 2; ++m2)
#pragma unroll
        for (int h4 = 0; h4 < 4; ++h4)
          eacc[m2][h4] = __builtin_amdgcn_mfma_f32_16x16x32_bf16(pa[m2], vf[h4], eacc[m2][h4], 0, 0, 0);
    }
  }
  // epilogue: normalized encoded (bf16)
#pragma unroll
  for (int m2 = 0; m2 < 2; ++m2)
#pragma unroll
    for (int h4 = 0; h4 < 4; ++h4)
#pragma unroll
      for (int r = 0; r < 4; ++r) {
        int t = wrow0 + m2 * 16 + l4 * 4 + r;
        int h = h4 * 16 + l15;
        enc[base + (size_t)t * NHC + h] = f2bf(eacc[m2][h4][r] * dinv[m2][r]);
      }
}

// ---------------------------------------------------------------------------
extern "C" void kernel_launch(void* const* d_in, const int* in_sizes, int n_in,
                              void* d_out, int out_size, void* d_ws, size_t ws_size,
                              hipStream_t stream) {
  const float* qv = (const float*)d_in[0];
  const float* kv = (const float*)d_in[1];
  const float* vv = (const float*)d_in[2];
  const float* wq = (const float*)d_in[3];
  const float* bq = (const float*)d_in[4];
  const float* wk = (const float*)d_in[5];
  const float* bk = (const float*)d_in[6];
  const float* wv = (const float*)d_in[7];
  const float* bv = (const float*)d_in[8];
  const float* wo = (const float*)d_in[9];
  const float* bo = (const float*)d_in[10];
  char* ws = (char*)d_ws;
  unsigned short* qb   = (unsigned short*)(ws + 0);
  unsigned short* kb   = (unsigned short*)(ws + 8388608);
  unsigned short* vb   = (unsigned short*)(ws + 16777216);
  unsigned short* vTb  = (unsigned short*)(ws + 25165824);
  unsigned short* wqT  = (unsigned short*)(ws + 33554432);
  unsigned short* wkT  = (unsigned short*)(ws + 35651584);
  unsigned short* wvT  = (unsigned short*)(ws + 37748736);
  unsigned short* woT  = (unsigned short*)(ws + 39845888);
  unsigned short* qinb = (unsigned short*)(ws + 41943040);
  unsigned short* kinb = (unsigned short*)(ws + 50331648);
  unsigned short* vinb = (unsigned short*)(ws + 58720256);
  unsigned short* enc  = (unsigned short*)(ws + 67371008);

  float* out = (float*)d_out;
  float* probs = out + (size_t)BB * TT * DD;

  conv_inputs<<<dim3(2048, 1, 3), 256, 0, stream>>>(qv, kv, vv, qinb, kinb, vinb);
  transpose_w<<<dim3(16, 16, 4), 256, 0, stream>>>(wq, wk, wv, wo, wqT, wkT, wvT, woT);
  gemm128<0><<<dim3(8, 32), 256, 0, stream>>>(qinb, wqT, bq, qb, 0.125f);  // H^-0.5 = 1/8
  gemm128<0><<<dim3(8, 32), 256, 0, stream>>>(kinb, wkT, bk, kb, 1.0f);
  gemm128<0><<<dim3(8, 32), 256, 0, stream>>>(vinb, wvT, bv, vb, 1.0f);
  transpose_v<<<dim3(32, 16, 2), 256, 0, stream>>>(vb, vTb);
  fused_attn<<<dim3(512), 256, 0, stream>>>(qb, kb, vTb, probs, enc);
  gemm128<1><<<dim3(8, 32), 256, 0, stream>>>(enc, woT, bo, out, 1.0f);
}

// Round 3
// 411.823 us; speedup vs baseline: 1.0394x; 1.0394x over previous
//
#include <hip/hip_runtime.h>

#define BB 2
#define TT 2048
#define DD 1024
#define NN 16
#define HH 64
#define NHC 1024   // N*H
#define CAPV 50.0f

typedef float f32x4 __attribute__((ext_vector_type(4)));
typedef __bf16 bf16x8 __attribute__((ext_vector_type(8)));
typedef unsigned short u16x8 __attribute__((ext_vector_type(8)));

// round-to-nearest-even f32 -> bf16 bits
__device__ __forceinline__ unsigned short f2bf(float f) {
  unsigned u = __builtin_bit_cast(unsigned, f);
  unsigned r = (u + 0x7fffu + ((u >> 16) & 1u)) >> 16;
  return (unsigned short)r;
}

// async global->LDS, 16B per lane; LDS dest must be wave-linear (base + lane*16)
__device__ __forceinline__ void gld16(void* lds, const void* g) {
  __builtin_amdgcn_global_load_lds(
      (__attribute__((address_space(1))) void*)(const_cast<void*>(g)),
      (__attribute__((address_space(3))) void*)(lds), 16, 0, 0);
}

// exp(CAP * tanh(l / CAP)) via u = exp(2l/CAP), tanh = (u-1)/(u+1)
__device__ __forceinline__ float captanh_exp(float l) {
  float u = __expf(l * (2.0f / CAPV));
  float ct = CAPV * (u - 1.0f) * __builtin_amdgcn_rcpf(u + 1.0f);
  return __expf(ct);
}

// ---------------------------------------------------------------------------
// f32 -> bf16 convert of the three input vectors
__global__ __launch_bounds__(256) void conv_inputs(
    const float* __restrict__ q, const float* __restrict__ k, const float* __restrict__ v,
    unsigned short* __restrict__ qo, unsigned short* __restrict__ ko, unsigned short* __restrict__ vo) {
  const float* src = blockIdx.z == 0 ? q : (blockIdx.z == 1 ? k : v);
  unsigned short* dst = blockIdx.z == 0 ? qo : (blockIdx.z == 1 ? ko : vo);
  size_t i = ((size_t)blockIdx.x * 256 + threadIdx.x) * 8;
  float4 a = *(const float4*)&src[i];
  float4 c = *(const float4*)&src[i + 4];
  u16x8 o;
  o[0] = f2bf(a.x); o[1] = f2bf(a.y); o[2] = f2bf(a.z); o[3] = f2bf(a.w);
  o[4] = f2bf(c.x); o[5] = f2bf(c.y); o[6] = f2bf(c.z); o[7] = f2bf(c.w);
  *(u16x8*)&dst[i] = o;
}

// transpose 1024x1024 f32 -> 1024x1024 bf16 (dst = src^T), z picks which weight
__global__ __launch_bounds__(256) void transpose_w(
    const float* __restrict__ wq, const float* __restrict__ wk,
    const float* __restrict__ wv, const float* __restrict__ wo,
    unsigned short* __restrict__ oq, unsigned short* __restrict__ ok,
    unsigned short* __restrict__ ov, unsigned short* __restrict__ oo) {
  __shared__ float tile[64][65];
  int z = blockIdx.z;
  const float* src = z == 0 ? wq : z == 1 ? wk : z == 2 ? wv : wo;
  unsigned short* dst = z == 0 ? oq : z == 1 ? ok : z == 2 ? ov : oo;
  int r0 = blockIdx.y * 64, c0 = blockIdx.x * 64;
  int tid = threadIdx.x;
#pragma unroll
  for (int i = 0; i < 16; ++i) {
    int idx = tid + 256 * i; int r = idx >> 6, c = idx & 63;
    tile[r][c] = src[(size_t)(r0 + r) * 1024 + c0 + c];
  }
  __syncthreads();
#pragma unroll
  for (int i = 0; i < 16; ++i) {
    int idx = tid + 256 * i; int rr = idx >> 6, cc = idx & 63;
    dst[(size_t)(c0 + rr) * 1024 + r0 + cc] = f2bf(tile[cc][rr]);
  }
}

// v [B,S,N,H] bf16 -> vT [B,N,H,S] bf16
__global__ __launch_bounds__(256) void transpose_v(
    const unsigned short* __restrict__ vb, unsigned short* __restrict__ vT) {
  __shared__ unsigned short tl[64][80];
  int s0 = blockIdx.x * 64, n = blockIdx.y, b = blockIdx.z;
  int tid = threadIdx.x;
  const size_t base = (size_t)b * TT * NHC + (size_t)n * HH;
#pragma unroll
  for (int i = 0; i < 2; ++i) {
    int c = tid + 256 * i; int r = c >> 3, g = c & 7;
    *(u16x8*)&tl[r][g * 8] = *(const u16x8*)&vb[base + (size_t)(s0 + r) * NHC + g * 8];
  }
  __syncthreads();
  const size_t vtb = (size_t)(b * NN + n) * HH * TT;
#pragma unroll
  for (int i = 0; i < 2; ++i) {
    int c = tid + 256 * i; int h = c >> 3, sg = c & 7;
    u16x8 w;
#pragma unroll
    for (int j = 0; j < 8; ++j) w[j] = tl[sg * 8 + j][h];
    *(u16x8*)&vT[vtb + (size_t)h * TT + s0 + sg * 8] = w;
  }
}

// ---------------------------------------------------------------------------
// 128x128-tile bf16 GEMM body, K=1024, BK=64, 4 waves (2x2), XOR-swizzled LDS.
// C[row, col] = sum_k A[row,k] * BT[col,k]; epilogue (acc+bias)*scale.
template <int OUT_F32>
__device__ __forceinline__ void gemm128_body(
    const unsigned short* __restrict__ A, const unsigned short* __restrict__ BT,
    const float* __restrict__ bias, void* __restrict__ Cout, float scale,
    int row0, int col0, unsigned short* As, unsigned short* Bs) {
  const int tid = threadIdx.x, lane = tid & 63, wave = tid >> 6;
  const int wm = wave >> 1, wn = wave & 1;
  const int l15 = lane & 15, l4 = lane >> 4;
  f32x4 acc[4][4] = {};
  for (int kt = 0; kt < 16; ++kt) {
    if (kt) __syncthreads();
#pragma unroll
    for (int i = 0; i < 4; ++i) {
      int c = tid + 256 * i; int r = c >> 3, g = (c & 7) ^ (r & 7);
      gld16(&As[c * 8], &A[(size_t)(row0 + r) * 1024 + kt * 64 + g * 8]);
    }
#pragma unroll
    for (int i = 0; i < 4; ++i) {
      int c = tid + 256 * i; int r = c >> 3, g = (c & 7) ^ (r & 7);
      gld16(&Bs[c * 8], &BT[(size_t)(col0 + r) * 1024 + kt * 64 + g * 8]);
    }
    __syncthreads();
#pragma unroll
    for (int ks = 0; ks < 2; ++ks) {
      bf16x8 af[4], bfr[4];
#pragma unroll
      for (int m = 0; m < 4; ++m) {
        int r = wm * 64 + m * 16 + l15;
        int ch = (ks * 4 + l4) ^ (r & 7);
        af[m] = *(const bf16x8*)&As[r * 64 + ch * 8];
      }
#pragma unroll
      for (int n = 0; n < 4; ++n) {
        int r = wn * 64 + n * 16 + l15;
        int ch = (ks * 4 + l4) ^ (r & 7);
        bfr[n] = *(const bf16x8*)&Bs[r * 64 + ch * 8];
      }
#pragma unroll
      for (int m = 0; m < 4; ++m)
#pragma unroll
        for (int n = 0; n < 4; ++n)
          acc[m][n] = __builtin_amdgcn_mfma_f32_16x16x32_bf16(af[m], bfr[n], acc[m][n], 0, 0, 0);
    }
  }
#pragma unroll
  for (int m = 0; m < 4; ++m)
#pragma unroll
    for (int n = 0; n < 4; ++n) {
      int col = col0 + wn * 64 + n * 16 + l15;
      float bv = bias[col];
#pragma unroll
      for (int r = 0; r < 4; ++r) {
        int row = row0 + wm * 64 + m * 16 + l4 * 4 + r;
        float v = (acc[m][n][r] + bv) * scale;
        if (OUT_F32) ((float*)Cout)[(size_t)row * 1024 + col] = v;
        else ((unsigned short*)Cout)[(size_t)row * 1024 + col] = f2bf(v);
      }
    }
}

// all three QKV projections in ONE launch (z selects), 768 blocks -> 3/CU
__global__ __launch_bounds__(256) void gemm_qkv(
    const unsigned short* __restrict__ Aq, const unsigned short* __restrict__ Ak,
    const unsigned short* __restrict__ Av,
    const unsigned short* __restrict__ Wq, const unsigned short* __restrict__ Wk,
    const unsigned short* __restrict__ Wv,
    const float* __restrict__ bq, const float* __restrict__ bk, const float* __restrict__ bv,
    unsigned short* __restrict__ Oq, unsigned short* __restrict__ Ok,
    unsigned short* __restrict__ Ov) {
  __shared__ unsigned short As[128 * 64];
  __shared__ unsigned short Bs[128 * 64];
  int z = blockIdx.z;
  const unsigned short* A = z == 0 ? Aq : z == 1 ? Ak : Av;
  const unsigned short* W = z == 0 ? Wq : z == 1 ? Wk : Wv;
  const float* bias = z == 0 ? bq : z == 1 ? bk : bv;
  unsigned short* C = z == 0 ? Oq : z == 1 ? Ok : Ov;
  float scale = z == 0 ? 0.125f : 1.0f;  // q scaled by H^-0.5 = 1/8
  gemm128_body<0>(A, W, bias, C, scale, blockIdx.y * 128, blockIdx.x * 128, As, Bs);
}

__global__ __launch_bounds__(256) void gemm_out(
    const unsigned short* __restrict__ A, const unsigned short* __restrict__ BT,
    const float* __restrict__ bias, float* __restrict__ Cout) {
  __shared__ unsigned short As[128 * 64];
  __shared__ unsigned short Bs[128 * 64];
  gemm128_body<1>(A, BT, bias, Cout, 1.0f, blockIdx.y * 128, blockIdx.x * 128, As, Bs);
}

// ---------------------------------------------------------------------------
// Pass 1: denom[b,n,t] = sum_s exp(CAP*tanh(qk/CAP))
// 512 threads = 8 waves x 16 q-rows; K double-buffered via global_load_lds,
// ONE __syncthreads per S-tile (its vmcnt(0) drain doubles as the load wait;
// stage(t+1) is issued AFTER the barrier so the drain targets loads issued a
// full compute-phase ago).
__global__ __launch_bounds__(512, 4) void attn_denom(
    const unsigned short* __restrict__ qb, const unsigned short* __restrict__ kb,
    float* __restrict__ denom) {
  __shared__ unsigned short K_lds[2][128 * 64];
  const int tid = threadIdx.x, lane = tid & 63, wave = tid >> 6;
  const int l15 = lane & 15, l4 = lane >> 4;
  const int bid = blockIdx.x;
  const int logical = (bid & 7) * 64 + (bid >> 3);  // 4 heads per XCD
  const int bt = logical & 15, head = logical >> 4;
  const int n = head & 15, b = head >> 4;
  const int wrow0 = bt * 128 + wave * 16;
  const size_t base = (size_t)b * TT * NHC + (size_t)n * HH;

  bf16x8 qf[2];
#pragma unroll
  for (int ks = 0; ks < 2; ++ks)
    qf[ks] = *(const bf16x8*)&qb[base + (size_t)(wrow0 + l15) * NHC + ks * 32 + l4 * 8];

  // prologue: stage tile 0 into buf 0 (2 x 16B per thread)
#pragma unroll
  for (int i = 0; i < 2; ++i) {
    int c = tid + 512 * i; int r = c >> 3, g = (c & 7) ^ (r & 7);
    gld16(&K_lds[0][c * 8], &kb[base + (size_t)r * NHC + g * 8]);
  }

  float psum[4] = {};
#pragma unroll 1
  for (int st = 0; st < 16; ++st) {
    __syncthreads();  // drains vmcnt -> K_lds[st&1] ready; all prior readers of the other buf done
    if (st < 15) {
      const int s1 = (st + 1) * 128;
      unsigned short* dstb = K_lds[(st + 1) & 1];
#pragma unroll
      for (int i = 0; i < 2; ++i) {
        int c = tid + 512 * i; int r = c >> 3, g = (c & 7) ^ (r & 7);
        gld16(&dstb[c * 8], &kb[base + (size_t)(s1 + r) * NHC + g * 8]);
      }
    }
    const unsigned short* KB = K_lds[st & 1];
    f32x4 acc[8] = {};
#pragma unroll
    for (int ks = 0; ks < 2; ++ks) {
      bf16x8 kf[8];
#pragma unroll
      for (int nf = 0; nf < 8; ++nf) {
        int r = nf * 16 + l15;
        int ch = (ks * 4 + l4) ^ (r & 7);
        kf[nf] = *(const bf16x8*)&KB[r * 64 + ch * 8];
      }
#pragma unroll
      for (int nf = 0; nf < 8; ++nf)
        acc[nf] = __builtin_amdgcn_mfma_f32_16x16x32_bf16(qf[ks], kf[nf], acc[nf], 0, 0, 0);
    }
#pragma unroll
    for (int nf = 0; nf < 8; ++nf)
#pragma unroll
      for (int r = 0; r < 4; ++r) psum[r] += captanh_exp(acc[nf][r]);
  }
  // reduce across the 16-lane column group
#pragma unroll
  for (int r = 0; r < 4; ++r) {
    float s = psum[r];
    s += __shfl_xor(s, 1);
    s += __shfl_xor(s, 2);
    s += __shfl_xor(s, 4);
    s += __shfl_xor(s, 8);
    if (l15 == 0) denom[((size_t)b * NN + n) * TT + wrow0 + l4 * 4 + r] = s;
  }
}

// ---------------------------------------------------------------------------
// Pass 2: probs (f32, normalized, direct register stores) + PV -> encoded.
// 512 threads = 8 waves x 16 q-rows; S-tile 64; K & V double-buffered via
// global_load_lds (1 x 16B per thread per buffer), ONE barrier per tile.
// P is wave-local LDS (stride 72 shorts), packed via shfl_xor+cvt_pk_bf16.
__global__ __launch_bounds__(512, 4) void attn_pv(
    const unsigned short* __restrict__ qb, const unsigned short* __restrict__ kb,
    const unsigned short* __restrict__ vT, const float* __restrict__ denom,
    float* __restrict__ probs, unsigned short* __restrict__ enc) {
  __shared__ unsigned short K_lds[2][64 * 64];
  __shared__ unsigned short V_lds[2][64 * 64];
  __shared__ unsigned short P_lds[8][16][72];
  const int tid = threadIdx.x, lane = tid & 63, wave = tid >> 6;
  const int l15 = lane & 15, l4 = lane >> 4;
  const int bid = blockIdx.x;
  const int logical = (bid & 7) * 64 + (bid >> 3);
  const int bt = logical & 15, head = logical >> 4;
  const int n = head & 15, b = head >> 4;
  const int wrow0 = bt * 128 + wave * 16;
  const size_t base = (size_t)b * TT * NHC + (size_t)n * HH;
  const size_t vtb = (size_t)(b * NN + n) * HH * TT;
  const size_t prow = (size_t)(b * NN + n) * TT;

  bf16x8 qf[2];
#pragma unroll
  for (int ks = 0; ks < 2; ++ks)
    qf[ks] = *(const bf16x8*)&qb[base + (size_t)(wrow0 + l15) * NHC + ks * 32 + l4 * 8];
  float dinv[4];
#pragma unroll
  for (int r = 0; r < 4; ++r)
    dinv[r] = 1.0f / denom[((size_t)b * NN + n) * TT + wrow0 + l4 * 4 + r];

  // prologue: stage tile 0 (K: 1 chunk/thread, V: 1 chunk/thread)
  {
    int c = tid; int r = c >> 3, g = (c & 7) ^ (r & 7);
    gld16(&K_lds[0][c * 8], &kb[base + (size_t)r * NHC + g * 8]);
    gld16(&V_lds[0][c * 8], &vT[vtb + (size_t)r * TT + g * 8]);
  }

  f32x4 eacc[4] = {};
  const bool evl = (l15 & 1) == 0;
#pragma unroll 1
  for (int st = 0; st < 32; ++st) {
    __syncthreads();  // drains stage(st) loads; syncs readers of buf being restaged
    if (st < 31) {
      const int s1 = (st + 1) * 64;
      const int bufn = (st + 1) & 1;
      int c = tid; int r = c >> 3, g = (c & 7) ^ (r & 7);
      gld16(&K_lds[bufn][c * 8], &kb[base + (size_t)(s1 + r) * NHC + g * 8]);
      gld16(&V_lds[bufn][c * 8], &vT[vtb + (size_t)r * TT + s1 + g * 8]);
    }
    const int s0 = st * 64;
    const unsigned short* KB = K_lds[st & 1];
    const unsigned short* VB = V_lds[st & 1];
    // QK^T
    f32x4 acc[4] = {};
#pragma unroll
    for (int ks = 0; ks < 2; ++ks) {
      bf16x8 kf[4];
#pragma unroll
      for (int nf = 0; nf < 4; ++nf) {
        int r = nf * 16 + l15;
        int ch = (ks * 4 + l4) ^ (r & 7);
        kf[nf] = *(const bf16x8*)&KB[r * 64 + ch * 8];
      }
#pragma unroll
      for (int nf = 0; nf < 4; ++nf)
        acc[nf] = __builtin_amdgcn_mfma_f32_16x16x32_bf16(qf[ks], kf[nf], acc[nf], 0, 0, 0);
    }
    // exp -> probs stores (f32 direct) + bf16 pack into wave-local P
#pragma unroll
    for (int r = 0; r < 4; ++r) {
      float ev[4];
#pragma unroll
      for (int nf = 0; nf < 4; ++nf) ev[nf] = captanh_exp(acc[nf][r]);
      size_t poff = (prow + (size_t)(wrow0 + l4 * 4 + r)) * TT + s0 + l15;
      float dv = dinv[r];
#pragma unroll
      for (int nf = 0; nf < 4; ++nf) probs[poff + nf * 16] = ev[nf] * dv;
      float pw[4];
#pragma unroll
      for (int nf = 0; nf < 4; ++nf) pw[nf] = __shfl_xor(ev[nf], 1);
      const int row = l4 * 4 + r;
#pragma unroll
      for (int jj = 0; jj < 2; ++jj) {
        int j = evl ? jj : jj + 2;
        float lo = evl ? ev[j] : pw[j];
        float hi = evl ? pw[j] : ev[j];
        unsigned pk;
        asm("v_cvt_pk_bf16_f32 %0, %1, %2" : "=v"(pk) : "v"(lo), "v"(hi));
        *(unsigned*)&P_lds[wave][row][j * 16 + (l15 & ~1)] = pk;
      }
    }
    asm volatile("s_waitcnt lgkmcnt(0)" ::: "memory");
    __builtin_amdgcn_sched_barrier(0);
    // PV: A = unnormalized P (wave-local), B = V from LDS; normalize at epilogue
#pragma unroll
    for (int kst = 0; kst < 2; ++kst) {
      bf16x8 pa = *(const bf16x8*)&P_lds[wave][l15][kst * 32 + l4 * 8];
      bf16x8 vf[4];
#pragma unroll
      for (int h4 = 0; h4 < 4; ++h4) {
        int h = h4 * 16 + l15;
        int ch = (kst * 4 + l4) ^ (h & 7);
        vf[h4] = *(const bf16x8*)&VB[h * 64 + ch * 8];
      }
#pragma unroll
      for (int h4 = 0; h4 < 4; ++h4)
        eacc[h4] = __builtin_amdgcn_mfma_f32_16x16x32_bf16(pa, vf[h4], eacc[h4], 0, 0, 0);
    }
  }
  // epilogue: normalized encoded (bf16)
#pragma unroll
  for (int h4 = 0; h4 < 4; ++h4)
#pragma unroll
    for (int r = 0; r < 4; ++r) {
      int t = wrow0 + l4 * 4 + r;
      int h = h4 * 16 + l15;
      enc[base + (size_t)t * NHC + h] = f2bf(eacc[h4][r] * dinv[r]);
    }
}

// ---------------------------------------------------------------------------
extern "C" void kernel_launch(void* const* d_in, const int* in_sizes, int n_in,
                              void* d_out, int out_size, void* d_ws, size_t ws_size,
                              hipStream_t stream) {
  const float* qv = (const float*)d_in[0];
  const float* kv = (const float*)d_in[1];
  const float* vv = (const float*)d_in[2];
  const float* wq = (const float*)d_in[3];
  const float* bq = (const float*)d_in[4];
  const float* wk = (const float*)d_in[5];
  const float* bk = (const float*)d_in[6];
  const float* wv = (const float*)d_in[7];
  const float* bv = (const float*)d_in[8];
  const float* wo = (const float*)d_in[9];
  const float* bo = (const float*)d_in[10];
  char* ws = (char*)d_ws;
  unsigned short* qb   = (unsigned short*)(ws + 0);
  unsigned short* kb   = (unsigned short*)(ws + 8388608);
  unsigned short* vb   = (unsigned short*)(ws + 16777216);
  unsigned short* vTb  = (unsigned short*)(ws + 25165824);
  unsigned short* wqT  = (unsigned short*)(ws + 33554432);
  unsigned short* wkT  = (unsigned short*)(ws + 35651584);
  unsigned short* wvT  = (unsigned short*)(ws + 37748736);
  unsigned short* woT  = (unsigned short*)(ws + 39845888);
  unsigned short* qinb = (unsigned short*)(ws + 41943040);
  unsigned short* kinb = (unsigned short*)(ws + 50331648);
  unsigned short* vinb = (unsigned short*)(ws + 58720256);
  float* denom         = (float*)(ws + 67108864);
  unsigned short* enc  = (unsigned short*)(ws + 67371008);

  float* out = (float*)d_out;
  float* probs = out + (size_t)BB * TT * DD;

  conv_inputs<<<dim3(2048, 1, 3), 256, 0, stream>>>(qv, kv, vv, qinb, kinb, vinb);
  transpose_w<<<dim3(16, 16, 4), 256, 0, stream>>>(wq, wk, wv, wo, wqT, wkT, wvT, woT);
  gemm_qkv<<<dim3(8, 32, 3), 256, 0, stream>>>(qinb, kinb, vinb, wqT, wkT, wvT,
                                               bq, bk, bv, qb, kb, vb);
  transpose_v<<<dim3(32, 16, 2), 256, 0, stream>>>(vb, vTb);
  attn_denom<<<dim3(512), 512, 0, stream>>>(qb, kb, denom);
  attn_pv<<<dim3(512), 512, 0, stream>>>(qb, kb, vTb, denom, probs, enc);
  gemm_out<<<dim3(8, 32), 256, 0, stream>>>(enc, woT, bo, out);
}

// Round 4
// 336.345 us; speedup vs baseline: 1.2726x; 1.2244x over previous
//
#include <hip/hip_runtime.h>

#define BB 2
#define TT 2048
#define DD 1024
#define NN 16
#define HH 64
#define NHC 1024   // N*H
#define CAPV 50.0f

typedef float f32x4 __attribute__((ext_vector_type(4)));
typedef __bf16 bf16x8 __attribute__((ext_vector_type(8)));
typedef unsigned short u16x8 __attribute__((ext_vector_type(8)));

// round-to-nearest-even f32 -> bf16 bits
__device__ __forceinline__ unsigned short f2bf(float f) {
  unsigned u = __builtin_bit_cast(unsigned, f);
  unsigned r = (u + 0x7fffu + ((u >> 16) & 1u)) >> 16;
  return (unsigned short)r;
}

// async global->LDS, 16B per lane; LDS dest must be wave-linear (base + lane*16)
__device__ __forceinline__ void gld16(void* lds, const void* g) {
  __builtin_amdgcn_global_load_lds(
      (__attribute__((address_space(1))) void*)(const_cast<void*>(g)),
      (__attribute__((address_space(3))) void*)(lds), 16, 0, 0);
}

// ---------------------------------------------------------------------------
// Merged prep: blocks [0,6144) = f32->bf16 convert of q/k/v inputs;
// blocks [6144,7168) = 64x64-tile transpose of the four weight matrices.
__global__ __launch_bounds__(256) void prep(
    const float* __restrict__ q, const float* __restrict__ k, const float* __restrict__ v,
    unsigned short* __restrict__ qo, unsigned short* __restrict__ ko, unsigned short* __restrict__ vo,
    const float* __restrict__ wq, const float* __restrict__ wk,
    const float* __restrict__ wv, const float* __restrict__ wo,
    unsigned short* __restrict__ oq, unsigned short* __restrict__ ok,
    unsigned short* __restrict__ ov, unsigned short* __restrict__ oo) {
  __shared__ float tile[64][65];
  const int bid = blockIdx.x;
  const int tid = threadIdx.x;
  if (bid < 6144) {
    const int z = bid >> 11, x = bid & 2047;
    const float* src = z == 0 ? q : (z == 1 ? k : v);
    unsigned short* dst = z == 0 ? qo : (z == 1 ? ko : vo);
    size_t i = ((size_t)x * 256 + tid) * 8;
    float4 a = *(const float4*)&src[i];
    float4 c = *(const float4*)&src[i + 4];
    u16x8 o;
    o[0] = f2bf(a.x); o[1] = f2bf(a.y); o[2] = f2bf(a.z); o[3] = f2bf(a.w);
    o[4] = f2bf(c.x); o[5] = f2bf(c.y); o[6] = f2bf(c.z); o[7] = f2bf(c.w);
    *(u16x8*)&dst[i] = o;
  } else {
    const int tw = bid - 6144;
    const int z = tw >> 8, rem = tw & 255;
    const int by = rem >> 4, bx = rem & 15;
    const float* src = z == 0 ? wq : z == 1 ? wk : z == 2 ? wv : wo;
    unsigned short* dst = z == 0 ? oq : z == 1 ? ok : z == 2 ? ov : oo;
    int r0 = by * 64, c0 = bx * 64;
#pragma unroll
    for (int i = 0; i < 16; ++i) {
      int idx = tid + 256 * i; int r = idx >> 6, c = idx & 63;
      tile[r][c] = src[(size_t)(r0 + r) * 1024 + c0 + c];
    }
    __syncthreads();
#pragma unroll
    for (int i = 0; i < 16; ++i) {
      int idx = tid + 256 * i; int rr = idx >> 6, cc = idx & 63;
      dst[(size_t)(c0 + rr) * 1024 + r0 + cc] = f2bf(tile[cc][rr]);
    }
  }
}

// v [B,S,N,H] bf16 -> vT [B,N,H,S] bf16
__global__ __launch_bounds__(256) void transpose_v(
    const unsigned short* __restrict__ vb, unsigned short* __restrict__ vT) {
  __shared__ unsigned short tl[64][80];
  int s0 = blockIdx.x * 64, n = blockIdx.y, b = blockIdx.z;
  int tid = threadIdx.x;
  const size_t base = (size_t)b * TT * NHC + (size_t)n * HH;
#pragma unroll
  for (int i = 0; i < 2; ++i) {
    int c = tid + 256 * i; int r = c >> 3, g = c & 7;
    *(u16x8*)&tl[r][g * 8] = *(const u16x8*)&vb[base + (size_t)(s0 + r) * NHC + g * 8];
  }
  __syncthreads();
  const size_t vtb = (size_t)(b * NN + n) * HH * TT;
#pragma unroll
  for (int i = 0; i < 2; ++i) {
    int c = tid + 256 * i; int h = c >> 3, sg = c & 7;
    u16x8 w;
#pragma unroll
    for (int j = 0; j < 8; ++j) w[j] = tl[sg * 8 + j][h];
    *(u16x8*)&vT[vtb + (size_t)h * TT + s0 + sg * 8] = w;
  }
}

// ---------------------------------------------------------------------------
// 128x128-tile bf16 GEMM body, K=1024, BK=64, 4 waves (2x2), XOR-swizzled LDS.
// C[row, col] = sum_k A[row,k] * BT[col,k]; epilogue (acc+bias)*scale.
template <int OUT_F32>
__device__ __forceinline__ void gemm128_body(
    const unsigned short* __restrict__ A, const unsigned short* __restrict__ BT,
    const float* __restrict__ bias, void* __restrict__ Cout, float scale,
    int row0, int col0, unsigned short* As, unsigned short* Bs) {
  const int tid = threadIdx.x, lane = tid & 63, wave = tid >> 6;
  const int wm = wave >> 1, wn = wave & 1;
  const int l15 = lane & 15, l4 = lane >> 4;
  f32x4 acc[4][4] = {};
  for (int kt = 0; kt < 16; ++kt) {
    if (kt) __syncthreads();
#pragma unroll
    for (int i = 0; i < 4; ++i) {
      int c = tid + 256 * i; int r = c >> 3, g = (c & 7) ^ (r & 7);
      gld16(&As[c * 8], &A[(size_t)(row0 + r) * 1024 + kt * 64 + g * 8]);
    }
#pragma unroll
    for (int i = 0; i < 4; ++i) {
      int c = tid + 256 * i; int r = c >> 3, g = (c & 7) ^ (r & 7);
      gld16(&Bs[c * 8], &BT[(size_t)(col0 + r) * 1024 + kt * 64 + g * 8]);
    }
    __syncthreads();
#pragma unroll
    for (int ks = 0; ks < 2; ++ks) {
      bf16x8 af[4], bfr[4];
#pragma unroll
      for (int m = 0; m < 4; ++m) {
        int r = wm * 64 + m * 16 + l15;
        int ch = (ks * 4 + l4) ^ (r & 7);
        af[m] = *(const bf16x8*)&As[r * 64 + ch * 8];
      }
#pragma unroll
      for (int n = 0; n < 4; ++n) {
        int r = wn * 64 + n * 16 + l15;
        int ch = (ks * 4 + l4) ^ (r & 7);
        bfr[n] = *(const bf16x8*)&Bs[r * 64 + ch * 8];
      }
#pragma unroll
      for (int m = 0; m < 4; ++m)
#pragma unroll
        for (int n = 0; n < 4; ++n)
          acc[m][n] = __builtin_amdgcn_mfma_f32_16x16x32_bf16(af[m], bfr[n], acc[m][n], 0, 0, 0);
    }
  }
#pragma unroll
  for (int m = 0; m < 4; ++m)
#pragma unroll
    for (int n = 0; n < 4; ++n) {
      int col = col0 + wn * 64 + n * 16 + l15;
      float bv = bias[col];
#pragma unroll
      for (int r = 0; r < 4; ++r) {
        int row = row0 + wm * 64 + m * 16 + l4 * 4 + r;
        float v = (acc[m][n][r] + bv) * scale;
        if (OUT_F32) ((float*)Cout)[(size_t)row * 1024 + col] = v;
        else ((unsigned short*)Cout)[(size_t)row * 1024 + col] = f2bf(v);
      }
    }
}

// all three QKV projections in ONE launch (z selects), 768 blocks -> 3/CU
__global__ __launch_bounds__(256) void gemm_qkv(
    const unsigned short* __restrict__ Aq, const unsigned short* __restrict__ Ak,
    const unsigned short* __restrict__ Av,
    const unsigned short* __restrict__ Wq, const unsigned short* __restrict__ Wk,
    const unsigned short* __restrict__ Wv,
    const float* __restrict__ bq, const float* __restrict__ bk, const float* __restrict__ bv,
    unsigned short* __restrict__ Oq, unsigned short* __restrict__ Ok,
    unsigned short* __restrict__ Ov) {
  __shared__ unsigned short As[128 * 64];
  __shared__ unsigned short Bs[128 * 64];
  int z = blockIdx.z;
  const unsigned short* A = z == 0 ? Aq : z == 1 ? Ak : Av;
  const unsigned short* W = z == 0 ? Wq : z == 1 ? Wk : Wv;
  const float* bias = z == 0 ? bq : z == 1 ? bk : bv;
  unsigned short* C = z == 0 ? Oq : z == 1 ? Ok : Ov;
  float scale = z == 0 ? 0.125f : 1.0f;  // q scaled by H^-0.5 = 1/8
  gemm128_body<0>(A, W, bias, C, scale, blockIdx.y * 128, blockIdx.x * 128, As, Bs);
}

__global__ __launch_bounds__(256) void gemm_out(
    const unsigned short* __restrict__ A, const unsigned short* __restrict__ BT,
    const float* __restrict__ bias, float* __restrict__ Cout) {
  __shared__ unsigned short As[128 * 64];
  __shared__ unsigned short Bs[128 * 64];
  gemm128_body<1>(A, BT, bias, Cout, 1.0f, blockIdx.y * 128, blockIdx.x * 128, As, Bs);
}

// ---------------------------------------------------------------------------
// Pass 1: denom[b,n,t] = sum_s exp(CAP*tanh(qk/CAP))   [R1 structure, verbatim]
__global__ __launch_bounds__(256) void attn_denom(
    const unsigned short* __restrict__ qb, const unsigned short* __restrict__ kb,
    float* __restrict__ denom) {
  __shared__ unsigned short q_lds[128 * 64];
  __shared__ unsigned short k_lds[128 * 64];
  __shared__ float rs[2][128];
  const int tid = threadIdx.x, lane = tid & 63, wave = tid >> 6;
  const int wm = wave >> 1, wn = wave & 1;
  const int l15 = lane & 15, l4 = lane >> 4;
  const int t0 = blockIdx.x * 128, n = blockIdx.y, b = blockIdx.z;
  const size_t base = (size_t)b * TT * NHC + (size_t)n * HH;
#pragma unroll
  for (int i = 0; i < 4; ++i) {
    int c = tid + 256 * i; int r = c >> 3, g = (c & 7) ^ (r & 7);
    gld16(&q_lds[c * 8], &qb[base + (size_t)(t0 + r) * NHC + g * 8]);
  }
  __syncthreads();
  bf16x8 qf[4][2];
#pragma unroll
  for (int m = 0; m < 4; ++m)
#pragma unroll
    for (int ks = 0; ks < 2; ++ks) {
      int r = wm * 64 + m * 16 + l15;
      int ch = (ks * 4 + l4) ^ (r & 7);
      qf[m][ks] = *(const bf16x8*)&q_lds[r * 64 + ch * 8];
    }
  float psum[4][4] = {};
  for (int st = 0; st < 16; ++st) {
    __syncthreads();
#pragma unroll
    for (int i = 0; i < 4; ++i) {
      int c = tid + 256 * i; int r = c >> 3, g = (c & 7) ^ (r & 7);
      gld16(&k_lds[c * 8], &kb[base + (size_t)(st * 128 + r) * NHC + g * 8]);
    }
    __syncthreads();
    f32x4 acc[4][4] = {};
#pragma unroll
    for (int ks = 0; ks < 2; ++ks) {
      bf16x8 bfr[4];
#pragma unroll
      for (int nf = 0; nf < 4; ++nf) {
        int r = wn * 64 + nf * 16 + l15;
        int ch = (ks * 4 + l4) ^ (r & 7);
        bfr[nf] = *(const bf16x8*)&k_lds[r * 64 + ch * 8];
      }
#pragma unroll
      for (int m = 0; m < 4; ++m)
#pragma unroll
        for (int nf = 0; nf < 4; ++nf)
          acc[m][nf] = __builtin_amdgcn_mfma_f32_16x16x32_bf16(qf[m][ks], bfr[nf], acc[m][nf], 0, 0, 0);
    }
#pragma unroll
    for (int m = 0; m < 4; ++m)
#pragma unroll
      for (int nf = 0; nf < 4; ++nf)
#pragma unroll
        for (int r = 0; r < 4; ++r) {
          float l = acc[m][nf][r];
          float u = __expf(l * (2.0f / CAPV));
          float ct = CAPV * (u - 1.0f) * __builtin_amdgcn_rcpf(u + 1.0f);
          psum[m][r] += __expf(ct);
        }
  }
#pragma unroll
  for (int m = 0; m < 4; ++m)
#pragma unroll
    for (int r = 0; r < 4; ++r) {
      float s = psum[m][r];
      s += __shfl_xor(s, 1);
      s += __shfl_xor(s, 2);
      s += __shfl_xor(s, 4);
      s += __shfl_xor(s, 8);
      if (l15 == 0) rs[wn][wm * 64 + m * 16 + l4 * 4 + r] = s;
    }
  __syncthreads();
  if (tid < 128) denom[((size_t)b * NN + n) * TT + t0 + tid] = rs[0][tid] + rs[1][tid];
}

// ---------------------------------------------------------------------------
// Pass 2: probs write (f32, normalized) + PV -> encoded (bf16)  [R1 verbatim]
__global__ __launch_bounds__(256) void attn_pv(
    const unsigned short* __restrict__ qb, const unsigned short* __restrict__ kb,
    const unsigned short* __restrict__ vT, const float* __restrict__ denom,
    float* __restrict__ probs, unsigned short* __restrict__ enc) {
  __shared__ unsigned short regA[64 * 128];    // q tile (128x64), then vT tile (64x128)
  __shared__ unsigned short regB[128 * 136];   // k tile (128x64) / P tile (128x[128+8])
  const int tid = threadIdx.x, lane = tid & 63, wave = tid >> 6;
  const int wm = wave >> 1, wn = wave & 1;
  const int l15 = lane & 15, l4 = lane >> 4;
  const int t0 = blockIdx.x * 128, n = blockIdx.y, b = blockIdx.z;
  const size_t base = (size_t)b * TT * NHC + (size_t)n * HH;
  const size_t vtb = (size_t)(b * NN + n) * HH * TT;
  const size_t prow = (size_t)(b * NN + n) * TT;
#pragma unroll
  for (int i = 0; i < 4; ++i) {
    int c = tid + 256 * i; int r = c >> 3, g = (c & 7) ^ (r & 7);
    gld16(&regA[c * 8], &qb[base + (size_t)(t0 + r) * NHC + g * 8]);
  }
  __syncthreads();
  bf16x8 qf[4][2];
#pragma unroll
  for (int m = 0; m < 4; ++m)
#pragma unroll
    for (int ks = 0; ks < 2; ++ks) {
      int r = wm * 64 + m * 16 + l15;
      int ch = (ks * 4 + l4) ^ (r & 7);
      qf[m][ks] = *(const bf16x8*)&regA[r * 64 + ch * 8];
    }
  float dinv[4][4];
#pragma unroll
  for (int m = 0; m < 4; ++m)
#pragma unroll
    for (int r = 0; r < 4; ++r)
      dinv[m][r] = 1.0f / denom[((size_t)b * NN + n) * TT + t0 + wm * 64 + m * 16 + l4 * 4 + r];
  __syncthreads();  // all q reads done before vT staging reuses regA
  f32x4 eacc[2][4] = {};
  for (int st = 0; st < 16; ++st) {
    const int s0 = st * 128;
#pragma unroll
    for (int i = 0; i < 4; ++i) {
      int c = tid + 256 * i; int r = c >> 3, g = (c & 7) ^ (r & 7);
      gld16(&regB[c * 8], &kb[base + (size_t)(s0 + r) * NHC + g * 8]);
    }
#pragma unroll
    for (int i = 0; i < 4; ++i) {
      int c = tid + 256 * i; int h = c >> 4, g = (c & 15) ^ (h & 15);
      gld16(&regA[c * 8], &vT[vtb + (size_t)h * TT + s0 + g * 8]);
    }
    __syncthreads();
    f32x4 acc[4][4] = {};
#pragma unroll
    for (int ks = 0; ks < 2; ++ks) {
      bf16x8 bfr[4];
#pragma unroll
      for (int nf = 0; nf < 4; ++nf) {
        int r = wn * 64 + nf * 16 + l15;
        int ch = (ks * 4 + l4) ^ (r & 7);
        bfr[nf] = *(const bf16x8*)&regB[r * 64 + ch * 8];
      }
#pragma unroll
      for (int m = 0; m < 4; ++m)
#pragma unroll
        for (int nf = 0; nf < 4; ++nf)
          acc[m][nf] = __builtin_amdgcn_mfma_f32_16x16x32_bf16(qf[m][ks], bfr[nf], acc[m][nf], 0, 0, 0);
    }
    __syncthreads();  // k reads complete before P overwrites regB
#pragma unroll
    for (int m = 0; m < 4; ++m)
#pragma unroll
      for (int nf = 0; nf < 4; ++nf) {
        int scol = wn * 64 + nf * 16 + l15;
#pragma unroll
        for (int r = 0; r < 4; ++r) {
          int trow = wm * 64 + m * 16 + l4 * 4 + r;
          float l = acc[m][nf][r];
          float u = __expf(l * (2.0f / CAPV));
          float ct = CAPV * (u - 1.0f) * __builtin_amdgcn_rcpf(u + 1.0f);
          float p = __expf(ct) * dinv[m][r];
          probs[(prow + t0 + trow) * (size_t)TT + s0 + scol] = p;
          regB[trow * 136 + scol] = f2bf(p);
        }
      }
    __syncthreads();  // P visible to all waves
#pragma unroll
    for (int kst = 0; kst < 4; ++kst) {
      bf16x8 pa[2], vbf[4];
#pragma unroll
      for (int m2 = 0; m2 < 2; ++m2) {
        int t = wave * 32 + m2 * 16 + l15;
        pa[m2] = *(const bf16x8*)&regB[t * 136 + kst * 32 + l4 * 8];
      }
#pragma unroll
      for (int h4 = 0; h4 < 4; ++h4) {
        int h = h4 * 16 + l15;
        int ch = (kst * 4 + l4) ^ (h & 15);
        vbf[h4] = *(const bf16x8*)&regA[h * 128 + ch * 8];
      }
#pragma unroll
      for (int m2 = 0; m2 < 2; ++m2)
#pragma unroll
        for (int h4 = 0; h4 < 4; ++h4)
          eacc[m2][h4] = __builtin_amdgcn_mfma_f32_16x16x32_bf16(pa[m2], vbf[h4], eacc[m2][h4], 0, 0, 0);
    }
    __syncthreads();  // PV reads done before next-iter staging
  }
#pragma unroll
  for (int m2 = 0; m2 < 2; ++m2)
#pragma unroll
    for (int h4 = 0; h4 < 4; ++h4)
#pragma unroll
      for (int r = 0; r < 4; ++r) {
        int t = t0 + wave * 32 + m2 * 16 + l4 * 4 + r;
        int h = h4 * 16 + l15;
        enc[base + (size_t)t * NHC + h] = f2bf(eacc[m2][h4][r]);
      }
}

// ---------------------------------------------------------------------------
extern "C" void kernel_launch(void* const* d_in, const int* in_sizes, int n_in,
                              void* d_out, int out_size, void* d_ws, size_t ws_size,
                              hipStream_t stream) {
  const float* qv = (const float*)d_in[0];
  const float* kv = (const float*)d_in[1];
  const float* vv = (const float*)d_in[2];
  const float* wq = (const float*)d_in[3];
  const float* bq = (const float*)d_in[4];
  const float* wk = (const float*)d_in[5];
  const float* bk = (const float*)d_in[6];
  const float* wv = (const float*)d_in[7];
  const float* bv = (const float*)d_in[8];
  const float* wo = (const float*)d_in[9];
  const float* bo = (const float*)d_in[10];
  char* ws = (char*)d_ws;
  unsigned short* qb   = (unsigned short*)(ws + 0);
  unsigned short* kb   = (unsigned short*)(ws + 8388608);
  unsigned short* vb   = (unsigned short*)(ws + 16777216);
  unsigned short* vTb  = (unsigned short*)(ws + 25165824);
  unsigned short* wqT  = (unsigned short*)(ws + 33554432);
  unsigned short* wkT  = (unsigned short*)(ws + 35651584);
  unsigned short* wvT  = (unsigned short*)(ws + 37748736);
  unsigned short* woT  = (unsigned short*)(ws + 39845888);
  unsigned short* qinb = (unsigned short*)(ws + 41943040);
  unsigned short* kinb = (unsigned short*)(ws + 50331648);
  unsigned short* vinb = (unsigned short*)(ws + 58720256);
  float* denom         = (float*)(ws + 67108864);
  unsigned short* enc  = (unsigned short*)(ws + 67371008);

  float* out = (float*)d_out;
  float* probs = out + (size_t)BB * TT * DD;

  prep<<<dim3(7168), 256, 0, stream>>>(qv, kv, vv, qinb, kinb, vinb,
                                       wq, wk, wv, wo, wqT, wkT, wvT, woT);
  gemm_qkv<<<dim3(8, 32, 3), 256, 0, stream>>>(qinb, kinb, vinb, wqT, wkT, wvT,
                                               bq, bk, bv, qb, kb, vb);
  transpose_v<<<dim3(32, 16, 2), 256, 0, stream>>>(vb, vTb);
  attn_denom<<<dim3(16, 16, 2), 256, 0, stream>>>(qb, kb, denom);
  attn_pv<<<dim3(16, 16, 2), 256, 0, stream>>>(qb, kb, vTb, denom, probs, enc);
  gemm_out<<<dim3(8, 32), 256, 0, stream>>>(enc, woT, bo, out);
}